// Round 9
// baseline (1583.338 us; speedup 1.0000x reference)
//
#include <hip/hip_runtime.h>
#include <hip/hip_bf16.h>
#include <math.h>

#define NN 100000
#define HID 128
#define EPSV 1e-5f

typedef short bf16x8 __attribute__((ext_vector_type(8)));
typedef float f32x4 __attribute__((ext_vector_type(4)));
typedef unsigned short u16;

__device__ __forceinline__ u16 f2b(float f) {       // f32 -> bf16 RNE
  unsigned u = __builtin_bit_cast(unsigned, f);
  u += 0x7FFFu + ((u >> 16) & 1u);
  return (u16)(u >> 16);
}
__device__ __forceinline__ float b2f(u16 h) {
  unsigned u = ((unsigned)h) << 16;
  return __builtin_bit_cast(float, u);
}

#define AS1(p) ((__attribute__((address_space(1))) void*)(p))
#define AS3(p) ((__attribute__((address_space(3))) void*)(p))

// ---------------- utility kernels ----------------

static __global__ void k_zero(float* __restrict__ p, int n) {
  int i = blockIdx.x * blockDim.x + threadIdx.x;
  if (i < n) p[i] = 0.f;
}

static __global__ void k_zero_i(int* __restrict__ p, int n) {
  int i = blockIdx.x * blockDim.x + threadIdx.x;
  if (i < n) p[i] = 0;
}

static __global__ void k_deg(const int* __restrict__ src, const int* __restrict__ dst,
                             int E, float* __restrict__ outdeg, float* __restrict__ indeg) {
  int e = blockIdx.x * blockDim.x + threadIdx.x;
  if (e < E) {
    atomicAdd(&outdeg[src[e]], 1.f);
    atomicAdd(&indeg[dst[e]], 1.f);
  }
}

static __global__ void k_counts(const float* __restrict__ indegRaw, int* __restrict__ counts, int n3) {
  int i = blockIdx.x * blockDim.x + threadIdx.x;
  if (i < n3) counts[i] = (int)indegRaw[i];
  else if (i == n3) counts[i] = 0;
}

static __global__ void k_rsqrt_clip(float* __restrict__ p, int n) {
  int i = blockIdx.x * blockDim.x + threadIdx.x;
  if (i < n) p[i] = rsqrtf(fmaxf(p[i], 1.f));
}

// ---------------- exclusive scan (two-level) ----------------
static __global__ void k_scan1(const int* __restrict__ in, int* __restrict__ out,
                               int* __restrict__ aux, int n) {
  __shared__ int s[256];
  int t = threadIdx.x, i = blockIdx.x * 256 + t;
  int v = (i < n) ? in[i] : 0;
  s[t] = v; __syncthreads();
#pragma unroll
  for (int d = 1; d < 256; d <<= 1) {
    int x = (t >= d) ? s[t - d] : 0;
    __syncthreads();
    s[t] += x;
    __syncthreads();
  }
  if (i < n) out[i] = s[t] - v;
  if (t == 255) aux[blockIdx.x] = s[255];
}

static __global__ void k_scan2(int* __restrict__ aux, int nb) {
  __shared__ int s[256];
  __shared__ int carry;
  int t = threadIdx.x;
  if (t == 0) carry = 0;
  __syncthreads();
  for (int base = 0; base < nb; base += 256) {
    int i = base + t;
    int v = (i < nb) ? aux[i] : 0;
    s[t] = v; __syncthreads();
#pragma unroll
    for (int d = 1; d < 256; d <<= 1) {
      int x = (t >= d) ? s[t - d] : 0;
      __syncthreads();
      s[t] += x;
      __syncthreads();
    }
    int excl = s[t] - v + carry;
    if (i < nb) aux[i] = excl;
    int tot = s[255];
    __syncthreads();
    if (t == 0) carry += tot;
    __syncthreads();
  }
}

static __global__ void k_scan3(int* __restrict__ out, const int* __restrict__ aux, int n) {
  int i = blockIdx.x * 256 + threadIdx.x;
  if (i < n) out[i] += aux[blockIdx.x];
}

static __global__ void k_fill(const int* __restrict__ src, const int* __restrict__ dst, int E,
                              const int* __restrict__ off, int* __restrict__ cur,
                              int rbase, int* __restrict__ srt) {
  int e = blockIdx.x * blockDim.x + threadIdx.x;
  if (e < E) {
    int d = dst[e];
    int p = off[rbase + d] + atomicAdd(&cur[rbase + d], 1);
    srt[p] = src[e];
  }
}

// W [3][K][128] f32 -> Wt [3*128][K] bf16 (row = rel*128 + outcol)
static __global__ void k_cvt_w(const float* __restrict__ W, u16* __restrict__ Wt, int K) {
  int i = blockIdx.x * blockDim.x + threadIdx.x;
  int tot = 3 * K * 128;
  if (i < tot) {
    int rel = i / (K * 128);
    int rem = i - rel * K * 128;
    int k = rem >> 7;
    int c = rem & 127;
    Wt[((size_t)rel * 128 + c) * K + k] = f2b(W[i]);
  }
}

// fcW [128][128] f32 -> Bt [c][k] bf16 (transposed)
static __global__ void k_cvt_fcw(const float* __restrict__ W, u16* __restrict__ Bt) {
  int i = blockIdx.x * blockDim.x + threadIdx.x;   // 16384
  if (i < 128 * 128) {
    int k = i >> 7, c = i & 127;
    Bt[c * 128 + k] = f2b(W[i]);
  }
}

// ---------------- all-register MFMA GEMM (no LDS, no barriers) ----------------
// Block = 4 independent waves (2m x 2n), each owns a 64x64 output tile of
// Y[row0..+128, rel*128..+128]. A/B fragments loaded straight from global to VGPRs
// (A row-major matches the MFMA fragment layout: lane -> row=l15, 16B of k at l4*8).
// Compiler auto-inserts counted vmcnt on the register deps -> natural pipeline,
// latency hidden by 1-step register double buffering + wave TLP. B is L2-resident
// (320 KB/rel); XCD swizzle co-locates the 3 rel-blocks of a row-tile for A sharing.
template<int K, bool AF32>
__global__ __launch_bounds__(256)
void k_gemm_reg(const void* __restrict__ Av,
                const u16* __restrict__ Wt,    // [3*128][K] bf16
                const float* __restrict__ sout,// [3][NN]
                u16* __restrict__ Y,           // [M][384] bf16
                int M, int NT)
{
  const int bid  = blockIdx.x;
  const int xcd  = bid & 7;
  const int sidx = bid >> 3;
  const int rel  = sidx % 3;
  const int tile = xcd + 8 * (sidx / 3);
  if (tile >= NT) return;
  const int row0 = tile * 128;

  const int t    = threadIdx.x;
  const int lane = t & 63;
  const int w    = t >> 6;          // 0..3
  const int wm   = w >> 1, wn = w & 1;
  const int l15  = lane & 15, l4 = lane >> 4;
  const int nk   = K / 32;

  const float* Af = (const float*)Av;
  const u16*   Ab = (const u16*)Av;
  const u16*   Wr = Wt + (size_t)rel * 128 * K;

  const float* ap[4];
  const u16*   abp[4];
  const u16*   bp[4];
#pragma unroll
  for (int m = 0; m < 4; ++m) {
    int r = row0 + wm * 64 + m * 16 + l15;
    if (r >= M) r = M - 1;                      // clamped dup read; write guarded below
    if constexpr (AF32) ap[m]  = Af + (size_t)r * K + l4 * 8;
    else                abp[m] = Ab + (size_t)r * K + l4 * 8;
  }
#pragma unroll
  for (int n = 0; n < 4; ++n)
    bp[n] = Wr + (size_t)(wn * 64 + n * 16 + l15) * K + l4 * 8;

  f32x4 acc[4][4];
#pragma unroll
  for (int m = 0; m < 4; ++m)
#pragma unroll
    for (int n = 0; n < 4; ++n) acc[m][n] = (f32x4){0.f, 0.f, 0.f, 0.f};

  f32x4  ra[4][2];       // next A raw (f32 path)
  bf16x8 a_nx[4];        // next A (bf16 path)
  bf16x8 b_nx[4];        // next B
  bf16x8 a_cu[4], b_cu[4];

  auto LOAD = [&](int k0) {
#pragma unroll
    for (int m = 0; m < 4; ++m) {
      if constexpr (AF32) {
        ra[m][0] = *(const f32x4*)(ap[m] + k0);
        ra[m][1] = *(const f32x4*)(ap[m] + k0 + 4);
      } else {
        a_nx[m] = *(const bf16x8*)(abp[m] + k0);
      }
    }
#pragma unroll
    for (int n = 0; n < 4; ++n) b_nx[n] = *(const bf16x8*)(bp[n] + k0);
  };

  auto CVT = [&]() {
#pragma unroll
    for (int m = 0; m < 4; ++m) {
      if constexpr (AF32) {
        union { bf16x8 v; u16 u[8]; } q;
#pragma unroll
        for (int j = 0; j < 4; ++j) {
          q.u[j]     = __builtin_bit_cast(u16, __float2bfloat16(ra[m][0][j]));
          q.u[4 + j] = __builtin_bit_cast(u16, __float2bfloat16(ra[m][1][j]));
        }
        a_cu[m] = q.v;
      } else {
        a_cu[m] = a_nx[m];
      }
    }
#pragma unroll
    for (int n = 0; n < 4; ++n) b_cu[n] = b_nx[n];
  };

  LOAD(0);
  CVT();

  for (int k = 0; k < nk; ++k) {
    if (k + 1 < nk) LOAD((k + 1) * 32);    // issued before the MFMA cluster; lands under it
#pragma unroll
    for (int m = 0; m < 4; ++m)
#pragma unroll
      for (int n = 0; n < 4; ++n)
        acc[m][n] = __builtin_amdgcn_mfma_f32_16x16x32_bf16(a_cu[m], b_cu[n], acc[m][n], 0, 0, 0);
    if (k + 1 < nk) CVT();                 // compiler places counted vmcnt here (reg deps)
  }

  // epilogue: C layout col=lane&15, row=(lane>>4)*4+reg
#pragma unroll
  for (int m = 0; m < 4; ++m) {
    const int rb = row0 + wm * 64 + m * 16 + l4 * 4;
#pragma unroll
    for (int j = 0; j < 4; ++j) {
      const int row = rb + j;
      if (row < M) {
        const float sc = sout[(size_t)rel * NN + row];
        u16* yp = Y + (size_t)row * 384 + rel * 128 + wn * 64 + l15;
#pragma unroll
        for (int n = 0; n < 4; ++n) yp[n * 16] = f2b(acc[m][n][j] * sc);
      }
    }
  }
}

// ---------------- CSR gather (4x unrolled for ILP on the L3 latency chain) ----------------
// writes acc as PACKED bf16 (u32 of 2 cols) for the MFMA FC that follows.
static __global__ __launch_bounds__(256)
void k_gather(const int* __restrict__ off, const int* __restrict__ srt,
              const float* __restrict__ sin_, const u16* __restrict__ Y,
              const float* __restrict__ b, u16* __restrict__ acc16)
{
  int d = blockIdx.x * 4 + (threadIdx.x >> 6);
  if (d >= NN) return;
  int c = (threadIdx.x & 63) * 2;
  float v0 = b[c]     + b[128 + c]     + b[256 + c];
  float v1 = b[c + 1] + b[128 + c + 1] + b[256 + c + 1];
#pragma unroll
  for (int r = 0; r < 3; ++r) {
    int base = r * NN + d;
    int j0 = off[base], j1 = off[base + 1];
    float p0 = 0.f, p1 = 0.f;
    int j = j0;
    for (; j + 4 <= j1; j += 4) {
      int s0 = srt[j], s1 = srt[j + 1], s2 = srt[j + 2], s3 = srt[j + 3];
      unsigned u0 = *(const unsigned*)&Y[(size_t)s0 * 384 + r * 128 + c];
      unsigned u1 = *(const unsigned*)&Y[(size_t)s1 * 384 + r * 128 + c];
      unsigned u2 = *(const unsigned*)&Y[(size_t)s2 * 384 + r * 128 + c];
      unsigned u3 = *(const unsigned*)&Y[(size_t)s3 * 384 + r * 128 + c];
      p0 += b2f((u16)(u0 & 0xFFFFu)) + b2f((u16)(u1 & 0xFFFFu))
          + b2f((u16)(u2 & 0xFFFFu)) + b2f((u16)(u3 & 0xFFFFu));
      p1 += b2f((u16)(u0 >> 16)) + b2f((u16)(u1 >> 16))
          + b2f((u16)(u2 >> 16)) + b2f((u16)(u3 >> 16));
    }
    for (; j < j1; ++j) {
      int s = srt[j];
      unsigned u = *(const unsigned*)&Y[(size_t)s * 384 + r * 128 + c];
      p0 += b2f((u16)(u & 0xFFFFu));
      p1 += b2f((u16)(u >> 16));
    }
    float sc = sin_[base];
    v0 += p0 * sc;
    v1 += p1 * sc;
  }
  unsigned out = (unsigned)f2b(v0) | ((unsigned)f2b(v1) << 16);
  *(unsigned*)&acc16[(size_t)d * 128 + c] = out;
}

// ---------------- FC (128x128) via MFMA: Z = relu(acc16 @ fcW + bias), f32 out ----------------
static __global__ __launch_bounds__(512)
void k_fc_mfma(const u16* __restrict__ A,      // [M][128] bf16
               const u16* __restrict__ Bt,     // [128][128] bf16 (row=outcol)
               const float* __restrict__ bias,
               float* __restrict__ Z, int M)
{
  __shared__ u16 Ab[4][4096];   // 32 KB: 4 ksteps x (128 rows x 32 k) frag-major

  const int row0 = blockIdx.x * 128;
  const int t    = threadIdx.x;
  const int lane = t & 63;
  const int w    = t >> 6;
  const int wm   = w >> 2;          // 0..1
  const int wn   = w & 3;           // 0..3
  const int l15  = lane & 15, l4 = lane >> 4;
  const int kl   = l4 * 8;

  int ar = row0 + w * 16 + l15;  if (ar >= M) ar = M - 1;

  bf16x8 br[2][4];
#pragma unroll
  for (int n = 0; n < 2; ++n)
#pragma unroll
    for (int ks = 0; ks < 4; ++ks)
      br[n][ks] = *(const bf16x8*)&Bt[(size_t)(wn * 32 + n * 16 + l15) * 128 + ks * 32 + kl];

#pragma unroll
  for (int ks = 0; ks < 4; ++ks)
    __builtin_amdgcn_global_load_lds(AS1(A + (size_t)ar * 128 + ks * 32 + kl),
                                     AS3(&Ab[ks][w * 512]), 16, 0, 0);

  asm volatile("s_waitcnt vmcnt(0)" ::: "memory");
  __syncthreads();

  f32x4 acc[4][2];
#pragma unroll
  for (int m = 0; m < 4; ++m) { acc[m][0] = (f32x4){0,0,0,0}; acc[m][1] = (f32x4){0,0,0,0}; }

#pragma unroll
  for (int ks = 0; ks < 4; ++ks) {
#pragma unroll
    for (int m = 0; m < 4; ++m) {
      bf16x8 a = *(const bf16x8*)&Ab[ks][(wm * 4 + m) * 512 + lane * 8];
      acc[m][0] = __builtin_amdgcn_mfma_f32_16x16x32_bf16(a, br[0][ks], acc[m][0], 0, 0, 0);
      acc[m][1] = __builtin_amdgcn_mfma_f32_16x16x32_bf16(a, br[1][ks], acc[m][1], 0, 0, 0);
    }
  }

#pragma unroll
  for (int m = 0; m < 4; ++m) {
    const int rb = row0 + wm * 64 + m * 16 + l4 * 4;
#pragma unroll
    for (int j = 0; j < 4; ++j) {
      const int row = rb + j;
      if (row < M) {
#pragma unroll
        for (int n = 0; n < 2; ++n) {
          const int cc = wn * 32 + n * 16 + l15;
          Z[(size_t)row * 128 + cc] = fmaxf(acc[m][n][j] + bias[cc], 0.f);
        }
      }
    }
  }
}

// ---------------- BatchNorm ----------------
static __global__ void k_bn_stats(const float* __restrict__ Z, int M, float* __restrict__ stats) {
  int col = threadIdx.x;  // 128
  float s = 0.f, s2 = 0.f;
  for (int row = blockIdx.x; row < M; row += gridDim.x) {
    float v = Z[(size_t)row * 128 + col];
    s += v;
    s2 += v * v;
  }
  atomicAdd(&stats[col], s);
  atomicAdd(&stats[128 + col], s2);
}

static __global__ void k_bn_finalize(const float* __restrict__ stats, int M,
                                     const float* __restrict__ g, const float* __restrict__ beta,
                                     float* __restrict__ ab) {
  int j = threadIdx.x;  // 128
  float m  = stats[j] / (float)M;
  float v  = stats[128 + j] / (float)M - m * m;
  float inv = rsqrtf(v + EPSV) * g[j];
  ab[j]       = inv;
  ab[128 + j] = beta[j] - m * inv;
}

template<bool OUT_BF16>
static __global__ void k_bn_apply(const float* __restrict__ Z, const float* __restrict__ ab,
                                  void* __restrict__ out, int n) {
  int i = blockIdx.x * blockDim.x + threadIdx.x;
  if (i < n) {
    int j = i & 127;
    float v = Z[i] * ab[j] + ab[128 + j];
    if constexpr (OUT_BF16) ((u16*)out)[i] = f2b(v);
    else                    ((float*)out)[i] = v;
  }
}

// ---------------- host-side layer driver ----------------

template<int K, bool AF32, bool OUT_BF16>
static void run_layer(const void* X,
                      const u16* Wt, const float* b,
                      const u16* fcWt, const float* fcb,
                      const float* g, const float* beta,
                      const int* off, const int* srt,
                      float* sOut, float* sIn, u16* Y, float* Z, u16* acc16,
                      float* stats, float* ab, void* out, hipStream_t stream)
{
  const int NT = (NN + 127) / 128;
  const int nblk = 24 * ((NT + 7) / 8);   // 8 XCD slots x 3 rels x ceil(NT/8)
  k_gemm_reg<K, AF32><<<nblk, 256, 0, stream>>>(X, Wt, sOut, Y, NN, NT);

  k_gather<<<(NN + 3) / 4, 256, 0, stream>>>(off, srt, sIn, Y, b, acc16);

  k_fc_mfma<<<NT, 512, 0, stream>>>(acc16, fcWt, fcb, Z, NN);

  k_zero<<<1, 256, 0, stream>>>(stats, 256);
  k_bn_stats<<<1024, 128, 0, stream>>>(Z, NN, stats);
  k_bn_finalize<<<1, 128, 0, stream>>>(stats, NN, g, beta, ab);
  k_bn_apply<OUT_BF16><<<(NN * HID + 255) / 256, 256, 0, stream>>>(Z, ab, out, NN * HID);
}

extern "C" void kernel_launch(void* const* d_in, const int* in_sizes, int n_in,
                              void* d_out, int out_size, void* d_ws, size_t ws_size,
                              hipStream_t stream)
{
  const float* x    = (const float*)d_in[0];
  const int*   seq  = (const int*)d_in[1];
  const int*   knn  = (const int*)d_in[2];
  const int*   dis  = (const int*)d_in[3];
  const float* W0   = (const float*)d_in[4];
  const float* b0   = (const float*)d_in[5];
  const float* fcW0 = (const float*)d_in[6];
  const float* fcb0 = (const float*)d_in[7];
  const float* g0   = (const float*)d_in[8];
  const float* be0  = (const float*)d_in[9];
  const float* W1   = (const float*)d_in[10];
  const float* b1   = (const float*)d_in[11];
  const float* fcW1 = (const float*)d_in[12];
  const float* fcb1 = (const float*)d_in[13];
  const float* g1   = (const float*)d_in[14];
  const float* be1  = (const float*)d_in[15];

  const int E[3] = { in_sizes[1] / 2, in_sizes[2] / 2, in_sizes[3] / 2 };
  const int* srcs[3] = { seq, knn, dis };

  const size_t N = NN;
  const int M3 = 3 * NN;

  float* ws    = (float*)d_ws;
  float* sOut  = ws;                        // 3N
  float* sIn   = sOut + 3 * N;              // 3N
  u16*   acc16 = (u16*)(sIn + 3 * N);       // N*128 bf16 (in former acc f32 region)
  float* accF  = (float*)acc16;             // region size N*128 f32
  float* stats = accF + N * 128;            // 256
  float* ab    = stats + 256;               // 256
  u16*   Y     = (u16*)(ab + 256);          // N*384 bf16 (Z aliases: Y dead after gather)
  float* Z     = (float*)Y;                 // N*128 f32
  u16*   h16   = Y + N * 384;               // N*128 bf16
  u16*   Wt0   = h16 + N * 128;             // 3*128*1280
  u16*   Wt1   = Wt0 + 3 * 128 * 1280;      // 3*128*128
  u16*   fcWt0 = Wt1 + 3 * 128 * 128;       // 128*128
  u16*   fcWt1 = fcWt0 + 128 * 128;         // 128*128
  int*   counts= (int*)(fcWt1 + 128 * 128);
  int*   off   = counts + (M3 + 1);
  int*   aux   = off + (M3 + 1);
  int*   cur   = aux + 1536;
  int*   srt   = cur + M3;                  // ETOT ints

  // weight transpose+convert
  k_cvt_w<<<(3 * 1280 * 128 + 255) / 256, 256, 0, stream>>>(W0, Wt0, 1280);
  k_cvt_w<<<(3 * 128 * 128 + 255) / 256, 256, 0, stream>>>(W1, Wt1, 128);
  k_cvt_fcw<<<(128 * 128 + 255) / 256, 256, 0, stream>>>(fcW0, fcWt0);
  k_cvt_fcw<<<(128 * 128 + 255) / 256, 256, 0, stream>>>(fcW1, fcWt1);

  // degrees
  k_zero<<<(6 * NN + 255) / 256, 256, 0, stream>>>(sOut, 6 * NN);
  for (int r = 0; r < 3; ++r) {
    k_deg<<<(E[r] + 255) / 256, 256, 0, stream>>>(
        srcs[r], srcs[r] + E[r], E[r], sOut + (size_t)r * N, sIn + (size_t)r * N);
  }
  k_counts<<<(M3 + 1 + 255) / 256, 256, 0, stream>>>(sIn, counts, M3);
  k_rsqrt_clip<<<(6 * NN + 255) / 256, 256, 0, stream>>>(sOut, 6 * NN);

  // CSR: exclusive scan of counts[M3+1] -> off
  const int nsc = M3 + 1;
  const int nb  = (nsc + 255) / 256;
  k_scan1<<<nb, 256, 0, stream>>>(counts, off, aux, nsc);
  k_scan2<<<1, 256, 0, stream>>>(aux, nb);
  k_scan3<<<nb, 256, 0, stream>>>(off, aux, nsc);

  k_zero_i<<<(M3 + 255) / 256, 256, 0, stream>>>(cur, M3);
  for (int r = 0; r < 3; ++r) {
    k_fill<<<(E[r] + 255) / 256, 256, 0, stream>>>(
        srcs[r], srcs[r] + E[r], E[r], off, cur, r * NN, srt);
  }

  // layer 0: x f32 [N,1280] -> h16 bf16 [N,128]
  run_layer<1280, true, true>(x, Wt0, b0, fcWt0, fcb0, g0, be0, off, srt,
                              sOut, sIn, Y, Z, acc16, stats, ab, h16, stream);

  // layer 1: h16 bf16 [N,128] -> d_out f32 [N,128]
  run_layer<128, false, false>(h16, Wt1, b1, fcWt1, fcb1, g1, be1, off, srt,
                               sOut, sIn, Y, Z, acc16, stats, ab, d_out, stream);
}

// Round 10
// 1265.473 us; speedup vs baseline: 1.2512x; 1.2512x over previous
//
#include <hip/hip_runtime.h>
#include <hip/hip_bf16.h>
#include <math.h>

#define NN 100000
#define HID 128
#define EPSV 1e-5f

typedef short bf16x8 __attribute__((ext_vector_type(8)));
typedef float f32x4 __attribute__((ext_vector_type(4)));
typedef unsigned short u16;

__device__ __forceinline__ u16 f2b(float f) {       // f32 -> bf16 RNE
  unsigned u = __builtin_bit_cast(unsigned, f);
  u += 0x7FFFu + ((u >> 16) & 1u);
  return (u16)(u >> 16);
}
__device__ __forceinline__ float b2f(u16 h) {
  unsigned u = ((unsigned)h) << 16;
  return __builtin_bit_cast(float, u);
}

#define AS1(p) ((__attribute__((address_space(1))) void*)(p))
#define AS3(p) ((__attribute__((address_space(3))) void*)(p))

// ---------------- utility kernels ----------------

static __global__ void k_zero(float* __restrict__ p, int n) {
  int i = blockIdx.x * blockDim.x + threadIdx.x;
  if (i < n) p[i] = 0.f;
}

static __global__ void k_zero_i(int* __restrict__ p, int n) {
  int i = blockIdx.x * blockDim.x + threadIdx.x;
  if (i < n) p[i] = 0;
}

static __global__ void k_deg(const int* __restrict__ src, const int* __restrict__ dst,
                             int E, float* __restrict__ outdeg, float* __restrict__ indeg) {
  int e = blockIdx.x * blockDim.x + threadIdx.x;
  if (e < E) {
    atomicAdd(&outdeg[src[e]], 1.f);
    atomicAdd(&indeg[dst[e]], 1.f);
  }
}

// counts[d] = total in-degree over the 3 relations (before rsqrt_clip); counts[n]=0
static __global__ void k_counts_tot(const float* __restrict__ indegRaw, int* __restrict__ counts, int n) {
  int i = blockIdx.x * blockDim.x + threadIdx.x;
  if (i < n) counts[i] = (int)(indegRaw[i] + indegRaw[n + i] + indegRaw[2 * n + i]);
  else if (i == n) counts[i] = 0;
}

static __global__ void k_rsqrt_clip(float* __restrict__ p, int n) {
  int i = blockIdx.x * blockDim.x + threadIdx.x;
  if (i < n) p[i] = rsqrtf(fmaxf(p[i], 1.f));
}

// ---------------- exclusive scan (two-level) ----------------
static __global__ void k_scan1(const int* __restrict__ in, int* __restrict__ out,
                               int* __restrict__ aux, int n) {
  __shared__ int s[256];
  int t = threadIdx.x, i = blockIdx.x * 256 + t;
  int v = (i < n) ? in[i] : 0;
  s[t] = v; __syncthreads();
#pragma unroll
  for (int d = 1; d < 256; d <<= 1) {
    int x = (t >= d) ? s[t - d] : 0;
    __syncthreads();
    s[t] += x;
    __syncthreads();
  }
  if (i < n) out[i] = s[t] - v;
  if (t == 255) aux[blockIdx.x] = s[255];
}

static __global__ void k_scan2(int* __restrict__ aux, int nb) {
  __shared__ int s[256];
  __shared__ int carry;
  int t = threadIdx.x;
  if (t == 0) carry = 0;
  __syncthreads();
  for (int base = 0; base < nb; base += 256) {
    int i = base + t;
    int v = (i < nb) ? aux[i] : 0;
    s[t] = v; __syncthreads();
#pragma unroll
    for (int d = 1; d < 256; d <<= 1) {
      int x = (t >= d) ? s[t - d] : 0;
      __syncthreads();
      s[t] += x;
      __syncthreads();
    }
    int excl = s[t] - v + carry;
    if (i < nb) aux[i] = excl;
    int tot = s[255];
    __syncthreads();
    if (t == 0) carry += tot;
    __syncthreads();
  }
}

static __global__ void k_scan3(int* __restrict__ out, const int* __restrict__ aux, int n) {
  int i = blockIdx.x * 256 + threadIdx.x;
  if (i < n) out[i] += aux[blockIdx.x];
}

// fill unified CSR: srt[off[dst] + cur[dst]++] = (src << 2) | rel
static __global__ void k_fill(const int* __restrict__ src, const int* __restrict__ dst, int E,
                              const int* __restrict__ off, int* __restrict__ cur,
                              int rel, int* __restrict__ srt) {
  int e = blockIdx.x * blockDim.x + threadIdx.x;
  if (e < E) {
    int d = dst[e];
    int p = off[d] + atomicAdd(&cur[d], 1);
    srt[p] = (src[e] << 2) | rel;
  }
}

// W [3][K][128] f32 -> Wt [3*128][K] bf16 (row = rel*128 + outcol)
static __global__ void k_cvt_w(const float* __restrict__ W, u16* __restrict__ Wt, int K) {
  int i = blockIdx.x * blockDim.x + threadIdx.x;
  int tot = 3 * K * 128;
  if (i < tot) {
    int rel = i / (K * 128);
    int rem = i - rel * K * 128;
    int k = rem >> 7;
    int c = rem & 127;
    Wt[((size_t)rel * 128 + c) * K + k] = f2b(W[i]);
  }
}

// fcW [128][128] f32 -> Bt [c][k] bf16 (transposed)
static __global__ void k_cvt_fcw(const float* __restrict__ W, u16* __restrict__ Bt) {
  int i = blockIdx.x * blockDim.x + threadIdx.x;   // 16384
  if (i < 128 * 128) {
    int k = i >> 7, c = i & 127;
    Bt[c * 128 + k] = f2b(W[i]);
  }
}

// ---------------- 3-buffer counted-vmcnt MFMA GEMM, 4 waves (256 thr) ----------------
// Rel-split: block computes Y[row0..+128, rel*128..+128]. Wave tile 64x64 (4x4 frags),
// acc = 64 regs -> VGPR ~132 total; LDS 72 KB (AF32) -> 2 independent blocks/CU.
// Per K-step: counted vmcnt (never drains mid-loop, 2-step prefetch depth) -> barrier ->
// STAGE(k+2) -> ds_read + 16 MFMA. XCD swizzle co-locates the 3 rel-blocks of a row tile.
template<int K, bool AF32>
__global__ __launch_bounds__(256)
void k_gemm2p(const void* __restrict__ Av,
              const u16* __restrict__ Wt,    // [3*128][K] bf16
              const float* __restrict__ sout,// [3][NN]
              u16* __restrict__ Y,           // [M][384] bf16
              int M, int NT)
{
  constexpr int A_U16 = AF32 ? 8192 : 4096;   // per-buffer A: 16 KB (f32) / 8 KB (bf16)
  constexpr int B_U16 = 4096;                 // per-buffer B: 8 KB
  __shared__ u16 lds[3][A_U16 + B_U16];       // 72 KB / 48 KB

  const int bid  = blockIdx.x;
  const int xcd  = bid & 7;
  const int sidx = bid >> 3;
  const int rel  = sidx % 3;
  const int tile = xcd + 8 * (sidx / 3);
  if (tile >= NT) return;
  const int row0 = tile * 128;

  const int t    = threadIdx.x;
  const int lane = t & 63;
  const int w    = t >> 6;          // 0..3
  const int wm   = w >> 1, wn = w & 1;
  const int l15  = lane & 15, l4 = lane >> 4;
  const int kl   = l4 * 8;
  const int nk   = K / 32;

  const u16* Wr = Wt + (size_t)rel * 128 * K;

  int r0 = row0 + (2 * w) * 16 + l15;      if (r0 >= M) r0 = M - 1;  // clamped dup read
  int r1 = row0 + (2 * w + 1) * 16 + l15;  if (r1 >= M) r1 = M - 1;

  const u16* gb0 = Wr + (size_t)((2 * w) * 16 + l15) * K + kl;
  const u16* gb1 = Wr + (size_t)((2 * w + 1) * 16 + l15) * K + kl;

  const float* Af = (const float*)Av;
  const u16*   Ab = (const u16*)Av;

  auto STAGE = [&](int buf, int k0) {
    u16* L = &lds[buf][0];
    if constexpr (AF32) {
      const float* sa0 = Af + (size_t)r0 * K + k0 + kl;
      const float* sa1 = Af + (size_t)r1 * K + k0 + kl;
      __builtin_amdgcn_global_load_lds(AS1(sa0),     AS3(L + (2 * w) * 1024),       16, 0, 0);
      __builtin_amdgcn_global_load_lds(AS1(sa0 + 4), AS3(L + (2 * w) * 1024 + 512), 16, 0, 0);
      __builtin_amdgcn_global_load_lds(AS1(sa1),     AS3(L + (2 * w + 1) * 1024),       16, 0, 0);
      __builtin_amdgcn_global_load_lds(AS1(sa1 + 4), AS3(L + (2 * w + 1) * 1024 + 512), 16, 0, 0);
    } else {
      const u16* sa0 = Ab + (size_t)r0 * K + k0 + kl;
      const u16* sa1 = Ab + (size_t)r1 * K + k0 + kl;
      __builtin_amdgcn_global_load_lds(AS1(sa0), AS3(L + (2 * w) * 512),     16, 0, 0);
      __builtin_amdgcn_global_load_lds(AS1(sa1), AS3(L + (2 * w + 1) * 512), 16, 0, 0);
    }
    u16* Bd = L + A_U16;
    __builtin_amdgcn_global_load_lds(AS1(gb0 + k0), AS3(Bd + (2 * w) * 512),     16, 0, 0);
    __builtin_amdgcn_global_load_lds(AS1(gb1 + k0), AS3(Bd + (2 * w + 1) * 512), 16, 0, 0);
  };

  f32x4 acc[4][4];
#pragma unroll
  for (int m = 0; m < 4; ++m)
#pragma unroll
    for (int n = 0; n < 4; ++n) acc[m][n] = (f32x4){0.f, 0.f, 0.f, 0.f};

  // prologue: 2-deep prefetch
  STAGE(0, 0);
  if (nk > 1) STAGE(1, 32);

  for (int k = 0; k < nk; ++k) {
    // wait until buffer k landed; keep the newest STAGE's loads in flight
    if (k + 1 < nk) {
      if constexpr (AF32) asm volatile("s_waitcnt vmcnt(6)" ::: "memory");
      else                asm volatile("s_waitcnt vmcnt(4)" ::: "memory");
    } else {
      asm volatile("s_waitcnt vmcnt(0)" ::: "memory");
    }
    __builtin_amdgcn_sched_barrier(0);
    __builtin_amdgcn_s_barrier();
    __builtin_amdgcn_sched_barrier(0);

    if (k + 2 < nk) STAGE((k + 2) % 3, (k + 2) * 32);

    const int cur = k % 3;
    bf16x8 a[4], b[4];
    if constexpr (AF32) {
      const float* Al = (const float*)&lds[cur][0];
#pragma unroll
      for (int m = 0; m < 4; ++m) {
        f32x4 lo = *(const f32x4*)&Al[(wm * 4 + m) * 512 + lane * 4];
        f32x4 hi = *(const f32x4*)&Al[(wm * 4 + m) * 512 + 256 + lane * 4];
        union { bf16x8 v; u16 u[8]; } q;
#pragma unroll
        for (int j = 0; j < 4; ++j) {
          q.u[j]     = __builtin_bit_cast(u16, __float2bfloat16(lo[j]));
          q.u[4 + j] = __builtin_bit_cast(u16, __float2bfloat16(hi[j]));
        }
        a[m] = q.v;
      }
    } else {
      const u16* Al = &lds[cur][0];
#pragma unroll
      for (int m = 0; m < 4; ++m) a[m] = *(const bf16x8*)&Al[(wm * 4 + m) * 512 + lane * 8];
    }
    {
      const u16* Bl = &lds[cur][A_U16];
#pragma unroll
      for (int n = 0; n < 4; ++n) b[n] = *(const bf16x8*)&Bl[(wn * 4 + n) * 512 + lane * 8];
    }

#pragma unroll
    for (int m = 0; m < 4; ++m)
#pragma unroll
      for (int n = 0; n < 4; ++n)
        acc[m][n] = __builtin_amdgcn_mfma_f32_16x16x32_bf16(a[m], b[n], acc[m][n], 0, 0, 0);
  }

  // epilogue: C layout col=lane&15, row=(lane>>4)*4+reg
#pragma unroll
  for (int m = 0; m < 4; ++m) {
    const int rb = row0 + wm * 64 + m * 16 + l4 * 4;
#pragma unroll
    for (int j = 0; j < 4; ++j) {
      const int row = rb + j;
      if (row < M) {
        const float sc = sout[(size_t)rel * NN + row];
        u16* yp = Y + (size_t)row * 384 + rel * 128 + wn * 64 + l15;
#pragma unroll
        for (int n = 0; n < 4; ++n) yp[n * 16] = f2b(acc[m][n][j] * sc);
      }
    }
  }
}

// ---------------- unified CSR gather (rel packed in tag, unroll 8) ----------------
// srt entry = (src<<2)|rel. One wave per node; lane holds cols {2l,2l+1}.
// Per-edge scale by sin_[rel][d] (distributes over the per-rel sum). Output packed bf16.
static __global__ __launch_bounds__(256)
void k_gather(const int* __restrict__ off, const int* __restrict__ srt,
              const float* __restrict__ sin_, const u16* __restrict__ Y,
              const float* __restrict__ b, u16* __restrict__ acc16)
{
  int d = blockIdx.x * 4 + (threadIdx.x >> 6);
  if (d >= NN) return;
  int c = (threadIdx.x & 63) * 2;
  float v0 = b[c]     + b[128 + c]     + b[256 + c];
  float v1 = b[c + 1] + b[128 + c + 1] + b[256 + c + 1];
  const float sc0 = sin_[d], sc1 = sin_[NN + d], sc2 = sin_[2 * NN + d];
  int j0 = off[d], j1 = off[d + 1];
  int j = j0;
  for (; j + 8 <= j1; j += 8) {
    unsigned uu[8];
    int rr[8];
#pragma unroll
    for (int q = 0; q < 8; ++q) {
      int tg = srt[j + q];
      rr[q] = tg & 3;
      uu[q] = *(const unsigned*)&Y[(size_t)(tg >> 2) * 384 + (size_t)rr[q] * 128 + c];
    }
#pragma unroll
    for (int q = 0; q < 8; ++q) {
      float s = (rr[q] == 0) ? sc0 : ((rr[q] == 1) ? sc1 : sc2);
      v0 = fmaf(b2f((u16)(uu[q] & 0xFFFFu)), s, v0);
      v1 = fmaf(b2f((u16)(uu[q] >> 16)), s, v1);
    }
  }
  for (; j < j1; ++j) {
    int tg = srt[j];
    int r = tg & 3;
    unsigned u = *(const unsigned*)&Y[(size_t)(tg >> 2) * 384 + (size_t)r * 128 + c];
    float s = (r == 0) ? sc0 : ((r == 1) ? sc1 : sc2);
    v0 = fmaf(b2f((u16)(u & 0xFFFFu)), s, v0);
    v1 = fmaf(b2f((u16)(u >> 16)), s, v1);
  }
  unsigned o = (unsigned)f2b(v0) | ((unsigned)f2b(v1) << 16);
  *(unsigned*)&acc16[(size_t)d * 128 + c] = o;
}

// ---------------- FC (128x128) via MFMA: Z = relu(acc16 @ fcW + bias), f32 out ----------------
static __global__ __launch_bounds__(512)
void k_fc_mfma(const u16* __restrict__ A,      // [M][128] bf16
               const u16* __restrict__ Bt,     // [128][128] bf16 (row=outcol)
               const float* __restrict__ bias,
               float* __restrict__ Z, int M)
{
  __shared__ u16 Ab[4][4096];   // 32 KB

  const int row0 = blockIdx.x * 128;
  const int t    = threadIdx.x;
  const int lane = t & 63;
  const int w    = t >> 6;
  const int wm   = w >> 2;          // 0..1
  const int wn   = w & 3;           // 0..3
  const int l15  = lane & 15, l4 = lane >> 4;
  const int kl   = l4 * 8;

  int ar = row0 + w * 16 + l15;  if (ar >= M) ar = M - 1;

  bf16x8 br[2][4];
#pragma unroll
  for (int n = 0; n < 2; ++n)
#pragma unroll
    for (int ks = 0; ks < 4; ++ks)
      br[n][ks] = *(const bf16x8*)&Bt[(size_t)(wn * 32 + n * 16 + l15) * 128 + ks * 32 + kl];

#pragma unroll
  for (int ks = 0; ks < 4; ++ks)
    __builtin_amdgcn_global_load_lds(AS1(A + (size_t)ar * 128 + ks * 32 + kl),
                                     AS3(&Ab[ks][w * 512]), 16, 0, 0);

  asm volatile("s_waitcnt vmcnt(0)" ::: "memory");
  __syncthreads();

  f32x4 acc[4][2];
#pragma unroll
  for (int m = 0; m < 4; ++m) { acc[m][0] = (f32x4){0,0,0,0}; acc[m][1] = (f32x4){0,0,0,0}; }

#pragma unroll
  for (int ks = 0; ks < 4; ++ks) {
#pragma unroll
    for (int m = 0; m < 4; ++m) {
      bf16x8 a = *(const bf16x8*)&Ab[ks][(wm * 4 + m) * 512 + lane * 8];
      acc[m][0] = __builtin_amdgcn_mfma_f32_16x16x32_bf16(a, br[0][ks], acc[m][0], 0, 0, 0);
      acc[m][1] = __builtin_amdgcn_mfma_f32_16x16x32_bf16(a, br[1][ks], acc[m][1], 0, 0, 0);
    }
  }

#pragma unroll
  for (int m = 0; m < 4; ++m) {
    const int rb = row0 + wm * 64 + m * 16 + l4 * 4;
#pragma unroll
    for (int j = 0; j < 4; ++j) {
      const int row = rb + j;
      if (row < M) {
#pragma unroll
        for (int n = 0; n < 2; ++n) {
          const int cc = wn * 32 + n * 16 + l15;
          Z[(size_t)row * 128 + cc] = fmaxf(acc[m][n][j] + bias[cc], 0.f);
        }
      }
    }
  }
}

// ---------------- BatchNorm ----------------
static __global__ void k_bn_stats(const float* __restrict__ Z, int M, float* __restrict__ stats) {
  int col = threadIdx.x;  // 128
  float s = 0.f, s2 = 0.f;
  for (int row = blockIdx.x; row < M; row += gridDim.x) {
    float v = Z[(size_t)row * 128 + col];
    s += v;
    s2 += v * v;
  }
  atomicAdd(&stats[col], s);
  atomicAdd(&stats[128 + col], s2);
}

static __global__ void k_bn_finalize(const float* __restrict__ stats, int M,
                                     const float* __restrict__ g, const float* __restrict__ beta,
                                     float* __restrict__ ab) {
  int j = threadIdx.x;  // 128
  float m  = stats[j] / (float)M;
  float v  = stats[128 + j] / (float)M - m * m;
  float inv = rsqrtf(v + EPSV) * g[j];
  ab[j]       = inv;
  ab[128 + j] = beta[j] - m * inv;
}

template<bool OUT_BF16>
static __global__ void k_bn_apply(const float* __restrict__ Z, const float* __restrict__ ab,
                                  void* __restrict__ out, int n) {
  int i = blockIdx.x * blockDim.x + threadIdx.x;
  if (i < n) {
    int j = i & 127;
    float v = Z[i] * ab[j] + ab[128 + j];
    if constexpr (OUT_BF16) ((u16*)out)[i] = f2b(v);
    else                    ((float*)out)[i] = v;
  }
}

// ---------------- host-side layer driver ----------------

template<int K, bool AF32, bool OUT_BF16>
static void run_layer(const void* X,
                      const u16* Wt, const float* b,
                      const u16* fcWt, const float* fcb,
                      const float* g, const float* beta,
                      const int* off, const int* srt,
                      float* sOut, float* sIn, u16* Y, float* Z, u16* acc16,
                      float* stats, float* ab, void* out, hipStream_t stream)
{
  const int NT = (NN + 127) / 128;
  const int nblk = 24 * ((NT + 7) / 8);   // 8 XCD slots x 3 rels x ceil(NT/8)
  k_gemm2p<K, AF32><<<nblk, 256, 0, stream>>>(X, Wt, sOut, Y, NN, NT);

  k_gather<<<(NN + 3) / 4, 256, 0, stream>>>(off, srt, sIn, Y, b, acc16);

  k_fc_mfma<<<NT, 512, 0, stream>>>(acc16, fcWt, fcb, Z, NN);

  k_zero<<<1, 256, 0, stream>>>(stats, 256);
  k_bn_stats<<<1024, 128, 0, stream>>>(Z, NN, stats);
  k_bn_finalize<<<1, 128, 0, stream>>>(stats, NN, g, beta, ab);
  k_bn_apply<OUT_BF16><<<(NN * HID + 255) / 256, 256, 0, stream>>>(Z, ab, out, NN * HID);
}

extern "C" void kernel_launch(void* const* d_in, const int* in_sizes, int n_in,
                              void* d_out, int out_size, void* d_ws, size_t ws_size,
                              hipStream_t stream)
{
  const float* x    = (const float*)d_in[0];
  const int*   seq  = (const int*)d_in[1];
  const int*   knn  = (const int*)d_in[2];
  const int*   dis  = (const int*)d_in[3];
  const float* W0   = (const float*)d_in[4];
  const float* b0   = (const float*)d_in[5];
  const float* fcW0 = (const float*)d_in[6];
  const float* fcb0 = (const float*)d_in[7];
  const float* g0   = (const float*)d_in[8];
  const float* be0  = (const float*)d_in[9];
  const float* W1   = (const float*)d_in[10];
  const float* b1   = (const float*)d_in[11];
  const float* fcW1 = (const float*)d_in[12];
  const float* fcb1 = (const float*)d_in[13];
  const float* g1   = (const float*)d_in[14];
  const float* be1  = (const float*)d_in[15];

  const int E[3] = { in_sizes[1] / 2, in_sizes[2] / 2, in_sizes[3] / 2 };
  const int* srcs[3] = { seq, knn, dis };

  const size_t N = NN;

  float* ws    = (float*)d_ws;
  float* sOut  = ws;                        // 3N
  float* sIn   = sOut + 3 * N;              // 3N
  u16*   acc16 = (u16*)(sIn + 3 * N);       // N*128 bf16 (region sized N*128 f32)
  float* accF  = (float*)acc16;
  float* stats = accF + N * 128;            // 256
  float* ab    = stats + 256;               // 256
  u16*   Y     = (u16*)(ab + 256);          // N*384 bf16 (Z aliases: Y dead after gather)
  float* Z     = (float*)Y;                 // N*128 f32
  u16*   h16   = Y + N * 384;               // N*128 bf16
  u16*   Wt0   = h16 + N * 128;             // 3*128*1280
  u16*   Wt1   = Wt0 + 3 * 128 * 1280;      // 3*128*128
  u16*   fcWt0 = Wt1 + 3 * 128 * 128;       // 128*128
  u16*   fcWt1 = fcWt0 + 128 * 128;         // 128*128
  int*   counts= (int*)(fcWt1 + 128 * 128); // N+1
  int*   off   = counts + (NN + 1);         // N+1
  int*   aux   = off + (NN + 1);            // scan aux
  int*   cur   = aux + 1536;                // N
  int*   srt   = cur + NN;                  // ETOT ints

  // weight transpose+convert
  k_cvt_w<<<(3 * 1280 * 128 + 255) / 256, 256, 0, stream>>>(W0, Wt0, 1280);
  k_cvt_w<<<(3 * 128 * 128 + 255) / 256, 256, 0, stream>>>(W1, Wt1, 128);
  k_cvt_fcw<<<(128 * 128 + 255) / 256, 256, 0, stream>>>(fcW0, fcWt0);
  k_cvt_fcw<<<(128 * 128 + 255) / 256, 256, 0, stream>>>(fcW1, fcWt1);

  // degrees (per relation, shared by both layers)
  k_zero<<<(6 * NN + 255) / 256, 256, 0, stream>>>(sOut, 6 * NN);
  for (int r = 0; r < 3; ++r) {
    k_deg<<<(E[r] + 255) / 256, 256, 0, stream>>>(
        srcs[r], srcs[r] + E[r], E[r], sOut + (size_t)r * N, sIn + (size_t)r * N);
  }
  // unified counts (total in-degree) from raw per-rel in-degrees, before clip
  k_counts_tot<<<(NN + 1 + 255) / 256, 256, 0, stream>>>(sIn, counts, NN);
  k_rsqrt_clip<<<(6 * NN + 255) / 256, 256, 0, stream>>>(sOut, 6 * NN);

  // CSR: exclusive scan of counts[N+1] -> off (off[N] = ETOT)
  const int nsc = NN + 1;
  const int nb  = (nsc + 255) / 256;
  k_scan1<<<nb, 256, 0, stream>>>(counts, off, aux, nsc);
  k_scan2<<<1, 256, 0, stream>>>(aux, nb);
  k_scan3<<<nb, 256, 0, stream>>>(off, aux, nsc);

  k_zero_i<<<(NN + 255) / 256, 256, 0, stream>>>(cur, NN);
  for (int r = 0; r < 3; ++r) {
    k_fill<<<(E[r] + 255) / 256, 256, 0, stream>>>(
        srcs[r], srcs[r] + E[r], E[r], off, cur, r, srt);
  }

  // layer 0: x f32 [N,1280] -> h16 bf16 [N,128]
  run_layer<1280, true, true>(x, Wt0, b0, fcWt0, fcb0, g0, be0, off, srt,
                              sOut, sIn, Y, Z, acc16, stats, ab, h16, stream);

  // layer 1: h16 bf16 [N,128] -> d_out f32 [N,128]
  run_layer<128, false, false>(h16, Wt1, b1, fcWt1, fcb1, g1, be1, off, srt,
                               sOut, sIn, Y, Z, acc16, stats, ab, d_out, stream);
}

// Round 11
// 1120.599 us; speedup vs baseline: 1.4129x; 1.1293x over previous
//
#include <hip/hip_runtime.h>
#include <hip/hip_bf16.h>
#include <math.h>

#define NN 100000
#define HID 128
#define EPSV 1e-5f

typedef short bf16x8 __attribute__((ext_vector_type(8)));
typedef float f32x4 __attribute__((ext_vector_type(4)));
typedef unsigned short u16;

__device__ __forceinline__ u16 f2b(float f) {       // f32 -> bf16 RNE
  unsigned u = __builtin_bit_cast(unsigned, f);
  u += 0x7FFFu + ((u >> 16) & 1u);
  return (u16)(u >> 16);
}
__device__ __forceinline__ float b2f(u16 h) {
  unsigned u = ((unsigned)h) << 16;
  return __builtin_bit_cast(float, u);
}

#define AS1(p) ((__attribute__((address_space(1))) void*)(p))
#define AS3(p) ((__attribute__((address_space(3))) void*)(p))

// ---------------- utility kernels ----------------

static __global__ void k_zero(float* __restrict__ p, int n) {
  int i = blockIdx.x * blockDim.x + threadIdx.x;
  if (i < n) p[i] = 0.f;
}

static __global__ void k_zero_i(int* __restrict__ p, int n) {
  int i = blockIdx.x * blockDim.x + threadIdx.x;
  if (i < n) p[i] = 0;
}

static __global__ void k_deg(const int* __restrict__ src, const int* __restrict__ dst,
                             int E, float* __restrict__ outdeg, float* __restrict__ indeg) {
  int e = blockIdx.x * blockDim.x + threadIdx.x;
  if (e < E) {
    atomicAdd(&outdeg[src[e]], 1.f);
    atomicAdd(&indeg[dst[e]], 1.f);
  }
}

// counts[d] = total in-degree over the 3 relations (before rsqrt_clip); counts[n]=0
static __global__ void k_counts_tot(const float* __restrict__ indegRaw, int* __restrict__ counts, int n) {
  int i = blockIdx.x * blockDim.x + threadIdx.x;
  if (i < n) counts[i] = (int)(indegRaw[i] + indegRaw[n + i] + indegRaw[2 * n + i]);
  else if (i == n) counts[i] = 0;
}

static __global__ void k_rsqrt_clip(float* __restrict__ p, int n) {
  int i = blockIdx.x * blockDim.x + threadIdx.x;
  if (i < n) p[i] = rsqrtf(fmaxf(p[i], 1.f));
}

// ---------------- exclusive scan (two-level) ----------------
static __global__ void k_scan1(const int* __restrict__ in, int* __restrict__ out,
                               int* __restrict__ aux, int n) {
  __shared__ int s[256];
  int t = threadIdx.x, i = blockIdx.x * 256 + t;
  int v = (i < n) ? in[i] : 0;
  s[t] = v; __syncthreads();
#pragma unroll
  for (int d = 1; d < 256; d <<= 1) {
    int x = (t >= d) ? s[t - d] : 0;
    __syncthreads();
    s[t] += x;
    __syncthreads();
  }
  if (i < n) out[i] = s[t] - v;
  if (t == 255) aux[blockIdx.x] = s[255];
}

static __global__ void k_scan2(int* __restrict__ aux, int nb) {
  __shared__ int s[256];
  __shared__ int carry;
  int t = threadIdx.x;
  if (t == 0) carry = 0;
  __syncthreads();
  for (int base = 0; base < nb; base += 256) {
    int i = base + t;
    int v = (i < nb) ? aux[i] : 0;
    s[t] = v; __syncthreads();
#pragma unroll
    for (int d = 1; d < 256; d <<= 1) {
      int x = (t >= d) ? s[t - d] : 0;
      __syncthreads();
      s[t] += x;
      __syncthreads();
    }
    int excl = s[t] - v + carry;
    if (i < nb) aux[i] = excl;
    int tot = s[255];
    __syncthreads();
    if (t == 0) carry += tot;
    __syncthreads();
  }
}

static __global__ void k_scan3(int* __restrict__ out, const int* __restrict__ aux, int n) {
  int i = blockIdx.x * 256 + threadIdx.x;
  if (i < n) out[i] += aux[blockIdx.x];
}

// fill unified CSR: srt[off[dst] + cur[dst]++] = (src << 2) | rel
static __global__ void k_fill(const int* __restrict__ src, const int* __restrict__ dst, int E,
                              const int* __restrict__ off, int* __restrict__ cur,
                              int rel, int* __restrict__ srt) {
  int e = blockIdx.x * blockDim.x + threadIdx.x;
  if (e < E) {
    int d = dst[e];
    int p = off[d] + atomicAdd(&cur[d], 1);
    srt[p] = (src[e] << 2) | rel;
  }
}

// W [3][K][128] f32 -> Wt [3*128][K] bf16 (row = rel*128 + outcol)
static __global__ void k_cvt_w(const float* __restrict__ W, u16* __restrict__ Wt, int K) {
  int i = blockIdx.x * blockDim.x + threadIdx.x;
  int tot = 3 * K * 128;
  if (i < tot) {
    int rel = i / (K * 128);
    int rem = i - rel * K * 128;
    int k = rem >> 7;
    int c = rem & 127;
    Wt[((size_t)rel * 128 + c) * K + k] = f2b(W[i]);
  }
}

// fcW [128][128] f32 -> Bt [c][k] bf16 (transposed)
static __global__ void k_cvt_fcw(const float* __restrict__ W, u16* __restrict__ Bt) {
  int i = blockIdx.x * blockDim.x + threadIdx.x;   // 16384
  if (i < 128 * 128) {
    int k = i >> 7, c = i & 127;
    Bt[c * 128 + k] = f2b(W[i]);
  }
}

// ---------------- pipelined fused MFMA GEMM (R6 structure, best measured: 299 us) ----------------
// Y[row, c] = sout[c>>7][row] * (A[row,:] @ Wt[c,:]);  BM=128 x BN=384, BK=32.
// 8 waves (2m x 4n), wave tile 64x96 (4x6 frags of 16x16x32). A staged once per tile for
// ALL 3 relations (the key amortization). 3 LDS buffers, 2-deep prefetch, counted vmcnt
// (never drains mid-loop), ONE s_barrier per K-step. No setprio (hurts lockstep GEMM).
template<int K, bool AF32>
__global__ __launch_bounds__(512)
void k_gemm_pipe(const void* __restrict__ Av,
                 const u16* __restrict__ Wt,    // [384][K] bf16
                 const float* __restrict__ sout,// [3][NN]
                 u16* __restrict__ Y,           // [M][384] bf16
                 int M)
{
  constexpr int A_BYTES = AF32 ? (128 * 32 * 4) : (128 * 32 * 2);  // 16 KB / 8 KB
  constexpr int B_BYTES = 384 * 32 * 2;                            // 24 KB
  constexpr int BUF_U16 = (A_BYTES + B_BYTES) / 2;
  __shared__ u16 lds[3][BUF_U16];   // 120 KB (AF32) / 96 KB

  const int row0 = blockIdx.x * 128;
  const int t    = threadIdx.x;
  const int lane = t & 63;
  const int w    = t >> 6;          // 0..7
  const int wm   = w >> 2;          // 0..1
  const int wn   = w & 3;           // 0..3
  const int l15  = lane & 15, l4 = lane >> 4;
  const int kl   = l4 * 8;
  const int nk   = K / 32;

  int ar = row0 + w * 16 + l15;  if (ar >= M) ar = M - 1;   // clamped dup read

  const float* Af = (const float*)Av;
  const u16*   Ab = (const u16*)Av;

  const u16* gb0 = Wt + (size_t)(w * 48 +      l15) * K + kl;
  const u16* gb1 = Wt + (size_t)(w * 48 + 16 + l15) * K + kl;
  const u16* gb2 = Wt + (size_t)(w * 48 + 32 + l15) * K + kl;

  auto STAGE = [&](int buf, int k0) {
    u16* L = &lds[buf][0];
    if constexpr (AF32) {
      const float* sa = Af + (size_t)ar * K + k0 + l4 * 8;
      __builtin_amdgcn_global_load_lds(AS1(sa),     AS3(L + (w * 2048) / 2),          16, 0, 0);
      __builtin_amdgcn_global_load_lds(AS1(sa + 4), AS3(L + (w * 2048 + 1024) / 2),   16, 0, 0);
    } else {
      const u16* sa = Ab + (size_t)ar * K + k0 + kl;
      __builtin_amdgcn_global_load_lds(AS1(sa),     AS3(L + (w * 1024) / 2),          16, 0, 0);
    }
    u16* Bd = L + A_BYTES / 2;
    __builtin_amdgcn_global_load_lds(AS1(gb0 + k0), AS3(Bd + (w * 3 + 0) * 512), 16, 0, 0);
    __builtin_amdgcn_global_load_lds(AS1(gb1 + k0), AS3(Bd + (w * 3 + 1) * 512), 16, 0, 0);
    __builtin_amdgcn_global_load_lds(AS1(gb2 + k0), AS3(Bd + (w * 3 + 2) * 512), 16, 0, 0);
  };

  f32x4 acc[4][6];
#pragma unroll
  for (int m = 0; m < 4; ++m)
#pragma unroll
    for (int n = 0; n < 6; ++n) acc[m][n] = (f32x4){0.f, 0.f, 0.f, 0.f};

  STAGE(0, 0);
  if (nk > 1) STAGE(1, 32);

  for (int k = 0; k < nk; ++k) {
    if (k + 1 < nk) {
      if constexpr (AF32) asm volatile("s_waitcnt vmcnt(5)" ::: "memory");
      else                asm volatile("s_waitcnt vmcnt(4)" ::: "memory");
    } else {
      asm volatile("s_waitcnt vmcnt(0)" ::: "memory");
    }
    __builtin_amdgcn_sched_barrier(0);
    __builtin_amdgcn_s_barrier();
    __builtin_amdgcn_sched_barrier(0);

    if (k + 2 < nk) STAGE((k + 2) % 3, (k + 2) * 32);

    const int cur = k % 3;
    bf16x8 a[4], b[6];
    if constexpr (AF32) {
      const float* Al = (const float*)&lds[cur][0];
#pragma unroll
      for (int m = 0; m < 4; ++m) {
        f32x4 lo = *(const f32x4*)&Al[(wm * 4 + m) * 512 + lane * 4];
        f32x4 hi = *(const f32x4*)&Al[(wm * 4 + m) * 512 + 256 + lane * 4];
        union { bf16x8 v; u16 u[8]; } q;
#pragma unroll
        for (int j = 0; j < 4; ++j) {
          q.u[j]     = __builtin_bit_cast(u16, __float2bfloat16(lo[j]));
          q.u[4 + j] = __builtin_bit_cast(u16, __float2bfloat16(hi[j]));
        }
        a[m] = q.v;
      }
    } else {
      const u16* Al = &lds[cur][0];
#pragma unroll
      for (int m = 0; m < 4; ++m) a[m] = *(const bf16x8*)&Al[(wm * 4 + m) * 512 + lane * 8];
    }
    {
      const u16* Bl = &lds[cur][A_BYTES / 2];
#pragma unroll
      for (int n = 0; n < 6; ++n) b[n] = *(const bf16x8*)&Bl[(wn * 6 + n) * 512 + lane * 8];
    }

#pragma unroll
    for (int m = 0; m < 4; ++m)
#pragma unroll
      for (int n = 0; n < 6; ++n)
        acc[m][n] = __builtin_amdgcn_mfma_f32_16x16x32_bf16(a[m], b[n], acc[m][n], 0, 0, 0);
  }

  // epilogue: C layout col=lane&15, row=(lane>>4)*4+reg
#pragma unroll
  for (int m = 0; m < 4; ++m) {
    const int rb = row0 + wm * 64 + m * 16 + l4 * 4;
#pragma unroll
    for (int j = 0; j < 4; ++j) {
      const int row = rb + j;
      if (row < M) {
        u16* yrow = Y + (size_t)row * 384;
#pragma unroll
        for (int n = 0; n < 6; ++n) {
          const int c = wn * 96 + n * 16;
          const float sc = sout[(size_t)(c >> 7) * NN + row];
          yrow[c + l15] = f2b(acc[m][n][j] * sc);
        }
      }
    }
  }
}

// ---------------- unified CSR gather (rel packed in tag, unroll 8) ----------------
static __global__ __launch_bounds__(256)
void k_gather(const int* __restrict__ off, const int* __restrict__ srt,
              const float* __restrict__ sin_, const u16* __restrict__ Y,
              const float* __restrict__ b, u16* __restrict__ acc16)
{
  int d = blockIdx.x * 4 + (threadIdx.x >> 6);
  if (d >= NN) return;
  int c = (threadIdx.x & 63) * 2;
  float v0 = b[c]     + b[128 + c]     + b[256 + c];
  float v1 = b[c + 1] + b[128 + c + 1] + b[256 + c + 1];
  const float sc0 = sin_[d], sc1 = sin_[NN + d], sc2 = sin_[2 * NN + d];
  int j0 = off[d], j1 = off[d + 1];
  int j = j0;
  for (; j + 8 <= j1; j += 8) {
    unsigned uu[8];
    int rr[8];
#pragma unroll
    for (int q = 0; q < 8; ++q) {
      int tg = srt[j + q];
      rr[q] = tg & 3;
      uu[q] = *(const unsigned*)&Y[(size_t)(tg >> 2) * 384 + (size_t)rr[q] * 128 + c];
    }
#pragma unroll
    for (int q = 0; q < 8; ++q) {
      float s = (rr[q] == 0) ? sc0 : ((rr[q] == 1) ? sc1 : sc2);
      v0 = fmaf(b2f((u16)(uu[q] & 0xFFFFu)), s, v0);
      v1 = fmaf(b2f((u16)(uu[q] >> 16)), s, v1);
    }
  }
  for (; j < j1; ++j) {
    int tg = srt[j];
    int r = tg & 3;
    unsigned u = *(const unsigned*)&Y[(size_t)(tg >> 2) * 384 + (size_t)r * 128 + c];
    float s = (r == 0) ? sc0 : ((r == 1) ? sc1 : sc2);
    v0 = fmaf(b2f((u16)(u & 0xFFFFu)), s, v0);
    v1 = fmaf(b2f((u16)(u >> 16)), s, v1);
  }
  unsigned o = (unsigned)f2b(v0) | ((unsigned)f2b(v1) << 16);
  *(unsigned*)&acc16[(size_t)d * 128 + c] = o;
}

// ---------------- FC (128x128) via MFMA + fused BN-stats ----------------
// Z = relu(acc16 @ fcW + bias); per-column sum/sumsq reduced in-wave (shfl over l4),
// then LDS, then one global atomicAdd per column per block. Eliminates k_bn_stats.
static __global__ __launch_bounds__(512)
void k_fc_mfma(const u16* __restrict__ A,      // [M][128] bf16
               const u16* __restrict__ Bt,     // [128][128] bf16 (row=outcol)
               const float* __restrict__ bias,
               float* __restrict__ Z, float* __restrict__ stats, int M)
{
  __shared__ u16 Ab[4][4096];   // 32 KB
  __shared__ float sst[256];

  const int row0 = blockIdx.x * 128;
  const int t    = threadIdx.x;
  const int lane = t & 63;
  const int w    = t >> 6;
  const int wm   = w >> 2;          // 0..1
  const int wn   = w & 3;           // 0..3
  const int l15  = lane & 15, l4 = lane >> 4;
  const int kl   = l4 * 8;

  if (t < 256) sst[t] = 0.f;

  int ar = row0 + w * 16 + l15;  if (ar >= M) ar = M - 1;

  bf16x8 br[2][4];
#pragma unroll
  for (int n = 0; n < 2; ++n)
#pragma unroll
    for (int ks = 0; ks < 4; ++ks)
      br[n][ks] = *(const bf16x8*)&Bt[(size_t)(wn * 32 + n * 16 + l15) * 128 + ks * 32 + kl];

#pragma unroll
  for (int ks = 0; ks < 4; ++ks)
    __builtin_amdgcn_global_load_lds(AS1(A + (size_t)ar * 128 + ks * 32 + kl),
                                     AS3(&Ab[ks][w * 512]), 16, 0, 0);

  asm volatile("s_waitcnt vmcnt(0)" ::: "memory");
  __syncthreads();

  f32x4 acc[4][2];
#pragma unroll
  for (int m = 0; m < 4; ++m) { acc[m][0] = (f32x4){0,0,0,0}; acc[m][1] = (f32x4){0,0,0,0}; }

#pragma unroll
  for (int ks = 0; ks < 4; ++ks) {
#pragma unroll
    for (int m = 0; m < 4; ++m) {
      bf16x8 a = *(const bf16x8*)&Ab[ks][(wm * 4 + m) * 512 + lane * 8];
      acc[m][0] = __builtin_amdgcn_mfma_f32_16x16x32_bf16(a, br[0][ks], acc[m][0], 0, 0, 0);
      acc[m][1] = __builtin_amdgcn_mfma_f32_16x16x32_bf16(a, br[1][ks], acc[m][1], 0, 0, 0);
    }
  }

  float ps[2] = {0.f, 0.f}, ps2[2] = {0.f, 0.f};
#pragma unroll
  for (int m = 0; m < 4; ++m) {
    const int rb = row0 + wm * 64 + m * 16 + l4 * 4;
#pragma unroll
    for (int j = 0; j < 4; ++j) {
      const int row = rb + j;
      const bool ok = row < M;
#pragma unroll
      for (int n = 0; n < 2; ++n) {
        const int cc = wn * 32 + n * 16 + l15;
        float v = ok ? fmaxf(acc[m][n][j] + bias[cc], 0.f) : 0.f;
        if (ok) Z[(size_t)row * 128 + cc] = v;
        ps[n]  += v;
        ps2[n] += v * v;
      }
    }
  }
  // reduce over the 4 lane-groups sharing a column (lanes l15 + {0,16,32,48})
#pragma unroll
  for (int n = 0; n < 2; ++n) {
    ps[n]  += __shfl_xor(ps[n], 16);  ps[n]  += __shfl_xor(ps[n], 32);
    ps2[n] += __shfl_xor(ps2[n], 16); ps2[n] += __shfl_xor(ps2[n], 32);
  }
  if (l4 == 0) {
#pragma unroll
    for (int n = 0; n < 2; ++n) {
      const int cc = wn * 32 + n * 16 + l15;
      atomicAdd(&sst[cc], ps[n]);
      atomicAdd(&sst[128 + cc], ps2[n]);
    }
  }
  __syncthreads();
  if (t < 256) atomicAdd(&stats[t], sst[t]);
}

// ---------------- BatchNorm finalize/apply ----------------
static __global__ void k_bn_finalize(const float* __restrict__ stats, int M,
                                     const float* __restrict__ g, const float* __restrict__ beta,
                                     float* __restrict__ ab) {
  int j = threadIdx.x;  // 128
  float m  = stats[j] / (float)M;
  float v  = stats[128 + j] / (float)M - m * m;
  float inv = rsqrtf(v + EPSV) * g[j];
  ab[j]       = inv;
  ab[128 + j] = beta[j] - m * inv;
}

template<bool OUT_BF16>
static __global__ void k_bn_apply(const float* __restrict__ Z, const float* __restrict__ ab,
                                  void* __restrict__ out, int n) {
  int i = blockIdx.x * blockDim.x + threadIdx.x;
  if (i < n) {
    int j = i & 127;
    float v = Z[i] * ab[j] + ab[128 + j];
    if constexpr (OUT_BF16) ((u16*)out)[i] = f2b(v);
    else                    ((float*)out)[i] = v;
  }
}

// ---------------- host-side layer driver ----------------

template<int K, bool AF32, bool OUT_BF16>
static void run_layer(const void* X,
                      const u16* Wt, const float* b,
                      const u16* fcWt, const float* fcb,
                      const float* g, const float* beta,
                      const int* off, const int* srt,
                      float* sOut, float* sIn, u16* Y, float* Z, u16* acc16,
                      float* stats, float* ab, void* out, hipStream_t stream)
{
  const int NT = (NN + 127) / 128;

  k_zero<<<1, 256, 0, stream>>>(stats, 256);          // before fc (stats fused there)

  k_gemm_pipe<K, AF32><<<NT, 512, 0, stream>>>(X, Wt, sOut, Y, NN);

  k_gather<<<(NN + 3) / 4, 256, 0, stream>>>(off, srt, sIn, Y, b, acc16);

  k_fc_mfma<<<NT, 512, 0, stream>>>(acc16, fcWt, fcb, Z, stats, NN);

  k_bn_finalize<<<1, 128, 0, stream>>>(stats, NN, g, beta, ab);
  k_bn_apply<OUT_BF16><<<(NN * HID + 255) / 256, 256, 0, stream>>>(Z, ab, out, NN * HID);
}

extern "C" void kernel_launch(void* const* d_in, const int* in_sizes, int n_in,
                              void* d_out, int out_size, void* d_ws, size_t ws_size,
                              hipStream_t stream)
{
  const float* x    = (const float*)d_in[0];
  const int*   seq  = (const int*)d_in[1];
  const int*   knn  = (const int*)d_in[2];
  const int*   dis  = (const int*)d_in[3];
  const float* W0   = (const float*)d_in[4];
  const float* b0   = (const float*)d_in[5];
  const float* fcW0 = (const float*)d_in[6];
  const float* fcb0 = (const float*)d_in[7];
  const float* g0   = (const float*)d_in[8];
  const float* be0  = (const float*)d_in[9];
  const float* W1   = (const float*)d_in[10];
  const float* b1   = (const float*)d_in[11];
  const float* fcW1 = (const float*)d_in[12];
  const float* fcb1 = (const float*)d_in[13];
  const float* g1   = (const float*)d_in[14];
  const float* be1  = (const float*)d_in[15];

  const int E[3] = { in_sizes[1] / 2, in_sizes[2] / 2, in_sizes[3] / 2 };
  const int* srcs[3] = { seq, knn, dis };

  const size_t N = NN;

  float* ws    = (float*)d_ws;
  float* sOut  = ws;                        // 3N
  float* sIn   = sOut + 3 * N;              // 3N
  u16*   acc16 = (u16*)(sIn + 3 * N);       // N*128 bf16 (region sized N*128 f32)
  float* accF  = (float*)acc16;
  float* stats = accF + N * 128;            // 256
  float* ab    = stats + 256;               // 256
  u16*   Y     = (u16*)(ab + 256);          // N*384 bf16 (Z aliases: Y dead after gather)
  float* Z     = (float*)Y;                 // N*128 f32
  u16*   h16   = Y + N * 384;               // N*128 bf16
  u16*   Wt0   = h16 + N * 128;             // 3*128*1280
  u16*   Wt1   = Wt0 + 3 * 128 * 1280;      // 3*128*128
  u16*   fcWt0 = Wt1 + 3 * 128 * 128;       // 128*128
  u16*   fcWt1 = fcWt0 + 128 * 128;         // 128*128
  int*   counts= (int*)(fcWt1 + 128 * 128); // N+1
  int*   off   = counts + (NN + 1);         // N+1
  int*   aux   = off + (NN + 1);            // scan aux
  int*   cur   = aux + 1536;                // N
  int*   srt   = cur + NN;                  // ETOT ints

  // weight transpose+convert
  k_cvt_w<<<(3 * 1280 * 128 + 255) / 256, 256, 0, stream>>>(W0, Wt0, 1280);
  k_cvt_w<<<(3 * 128 * 128 + 255) / 256, 256, 0, stream>>>(W1, Wt1, 128);
  k_cvt_fcw<<<(128 * 128 + 255) / 256, 256, 0, stream>>>(fcW0, fcWt0);
  k_cvt_fcw<<<(128 * 128 + 255) / 256, 256, 0, stream>>>(fcW1, fcWt1);

  // degrees (per relation, shared by both layers)
  k_zero<<<(6 * NN + 255) / 256, 256, 0, stream>>>(sOut, 6 * NN);
  for (int r = 0; r < 3; ++r) {
    k_deg<<<(E[r] + 255) / 256, 256, 0, stream>>>(
        srcs[r], srcs[r] + E[r], E[r], sOut + (size_t)r * N, sIn + (size_t)r * N);
  }
  k_counts_tot<<<(NN + 1 + 255) / 256, 256, 0, stream>>>(sIn, counts, NN);
  k_rsqrt_clip<<<(6 * NN + 255) / 256, 256, 0, stream>>>(sOut, 6 * NN);

  // unified CSR: exclusive scan of counts[N+1] -> off (off[N] = ETOT)
  const int nsc = NN + 1;
  const int nb  = (nsc + 255) / 256;
  k_scan1<<<nb, 256, 0, stream>>>(counts, off, aux, nsc);
  k_scan2<<<1, 256, 0, stream>>>(aux, nb);
  k_scan3<<<nb, 256, 0, stream>>>(off, aux, nsc);

  k_zero_i<<<(NN + 255) / 256, 256, 0, stream>>>(cur, NN);
  for (int r = 0; r < 3; ++r) {
    k_fill<<<(E[r] + 255) / 256, 256, 0, stream>>>(
        srcs[r], srcs[r] + E[r], E[r], off, cur, r, srt);
  }

  // layer 0: x f32 [N,1280] -> h16 bf16 [N,128]
  run_layer<1280, true, true>(x, Wt0, b0, fcWt0, fcb0, g0, be0, off, srt,
                              sOut, sIn, Y, Z, acc16, stats, ab, h16, stream);

  // layer 1: h16 bf16 [N,128] -> d_out f32 [N,128]
  run_layer<128, false, false>(h16, Wt1, b1, fcWt1, fcb1, g1, be1, off, srt,
                               sOut, sIn, Y, Z, acc16, stats, ab, d_out, stream);
}

// Round 12
// 1093.819 us; speedup vs baseline: 1.4475x; 1.0245x over previous
//
#include <hip/hip_runtime.h>
#include <hip/hip_bf16.h>
#include <math.h>

#define NN 100000
#define HID 128
#define EPSV 1e-5f

typedef short bf16x8 __attribute__((ext_vector_type(8)));
typedef float f32x4 __attribute__((ext_vector_type(4)));
typedef unsigned short u16;

__device__ __forceinline__ u16 f2b(float f) {       // f32 -> bf16 RNE
  unsigned u = __builtin_bit_cast(unsigned, f);
  u += 0x7FFFu + ((u >> 16) & 1u);
  return (u16)(u >> 16);
}
__device__ __forceinline__ float b2f(u16 h) {
  unsigned u = ((unsigned)h) << 16;
  return __builtin_bit_cast(float, u);
}

#define AS1(p) ((__attribute__((address_space(1))) void*)(p))
#define AS3(p) ((__attribute__((address_space(3))) void*)(p))

// ---------------- fused init: zero degree arrays, stats (both layers), cursors ----------------
static __global__ void k_init(float* __restrict__ degs, int n6,
                              int* __restrict__ cur, int nc,
                              float* __restrict__ stats, int ns) {
  int i = blockIdx.x * blockDim.x + threadIdx.x;
  if (i < n6) degs[i] = 0.f;
  if (i < nc) cur[i] = 0;
  if (i < ns) stats[i] = 0.f;
}

// ---------------- fused degree histogram over all 3 edge lists ----------------
static __global__ void k_deg_all(const int* __restrict__ seq, const int* __restrict__ knn,
                                 const int* __restrict__ dis, int E0, int E1, int E2,
                                 float* __restrict__ sOut, float* __restrict__ sIn) {
  int e = blockIdx.x * blockDim.x + threadIdx.x;
  int rel, eo;
  const int *src, *dst;
  if (e < E0)            { rel = 0; eo = e;           src = seq; dst = seq + E0; }
  else if (e < E0 + E1)  { rel = 1; eo = e - E0;      src = knn; dst = knn + E1; }
  else if (e < E0+E1+E2) { rel = 2; eo = e - E0 - E1; src = dis; dst = dis + E2; }
  else return;
  atomicAdd(&sOut[(size_t)rel * NN + src[eo]], 1.f);
  atomicAdd(&sIn[(size_t)rel * NN + dst[eo]], 1.f);
}

// ---------------- exclusive scan (two-level); scan1 computes counts inline ----------------
static __global__ void k_scan1_c(const float* __restrict__ indegRaw, int* __restrict__ out,
                                 int* __restrict__ aux, int n) {   // n = NN+1
  __shared__ int s[256];
  int t = threadIdx.x, i = blockIdx.x * 256 + t;
  int v = 0;
  if (i < NN) v = (int)(indegRaw[i] + indegRaw[NN + i] + indegRaw[2 * NN + i]);
  s[t] = v; __syncthreads();
#pragma unroll
  for (int d = 1; d < 256; d <<= 1) {
    int x = (t >= d) ? s[t - d] : 0;
    __syncthreads();
    s[t] += x;
    __syncthreads();
  }
  if (i < n) out[i] = s[t] - v;
  if (t == 255) aux[blockIdx.x] = s[255];
}

static __global__ void k_scan2(int* __restrict__ aux, int nb) {
  __shared__ int s[256];
  __shared__ int carry;
  int t = threadIdx.x;
  if (t == 0) carry = 0;
  __syncthreads();
  for (int base = 0; base < nb; base += 256) {
    int i = base + t;
    int v = (i < nb) ? aux[i] : 0;
    s[t] = v; __syncthreads();
#pragma unroll
    for (int d = 1; d < 256; d <<= 1) {
      int x = (t >= d) ? s[t - d] : 0;
      __syncthreads();
      s[t] += x;
      __syncthreads();
    }
    int excl = s[t] - v + carry;
    if (i < nb) aux[i] = excl;
    int tot = s[255];
    __syncthreads();
    if (t == 0) carry += tot;
    __syncthreads();
  }
}

static __global__ void k_scan3(int* __restrict__ out, const int* __restrict__ aux, int n) {
  int i = blockIdx.x * 256 + threadIdx.x;
  if (i < n) out[i] += aux[blockIdx.x];
}

// ---------------- fused CSR fill over all 3 edge lists: srt = (src<<2)|rel ----------------
static __global__ void k_fill_all(const int* __restrict__ seq, const int* __restrict__ knn,
                                  const int* __restrict__ dis, int E0, int E1, int E2,
                                  const int* __restrict__ off, int* __restrict__ cur,
                                  int* __restrict__ srt) {
  int e = blockIdx.x * blockDim.x + threadIdx.x;
  int rel, eo;
  const int *src, *dst;
  if (e < E0)            { rel = 0; eo = e;           src = seq; dst = seq + E0; }
  else if (e < E0 + E1)  { rel = 1; eo = e - E0;      src = knn; dst = knn + E1; }
  else if (e < E0+E1+E2) { rel = 2; eo = e - E0 - E1; src = dis; dst = dis + E2; }
  else return;
  int d = dst[eo];
  int p = off[d] + atomicAdd(&cur[d], 1);
  srt[p] = (src[eo] << 2) | rel;
}

// ---------------- fused weight convert: Wt0 [384][1280], Wt1 [384][128], fcWt0/1 [128][128] ----------------
static __global__ void k_cvt_all(const float* __restrict__ W0, const float* __restrict__ W1,
                                 const float* __restrict__ fcW0, const float* __restrict__ fcW1,
                                 u16* __restrict__ Wt0, u16* __restrict__ Wt1,
                                 u16* __restrict__ fcWt0, u16* __restrict__ fcWt1) {
  const int N0 = 3 * 1280 * 128, N1 = 3 * 128 * 128, N2 = 128 * 128;
  int i = blockIdx.x * blockDim.x + threadIdx.x;
  if (i < N0) {                 // W0 [3][1280][128] -> Wt0 [(rel*128+c)][1280]
    int rel = i / (1280 * 128);
    int rem = i - rel * 1280 * 128;
    int k = rem >> 7, c = rem & 127;
    Wt0[((size_t)rel * 128 + c) * 1280 + k] = f2b(W0[i]);
  } else if (i < N0 + N1) {     // W1 [3][128][128] -> Wt1 [(rel*128+c)][128]
    int j = i - N0;
    int rel = j / (128 * 128);
    int rem = j - rel * 128 * 128;
    int k = rem >> 7, c = rem & 127;
    Wt1[((size_t)rel * 128 + c) * 128 + k] = f2b(W1[j]);
  } else if (i < N0 + N1 + N2) {
    int j = i - N0 - N1;
    int k = j >> 7, c = j & 127;
    fcWt0[c * 128 + k] = f2b(fcW0[j]);
  } else if (i < N0 + N1 + 2 * N2) {
    int j = i - N0 - N1 - N2;
    int k = j >> 7, c = j & 127;
    fcWt1[c * 128 + k] = f2b(fcW1[j]);
  }
}

// ---------------- pipelined fused MFMA GEMM (R6/R11 structure, best measured: 299 us) ----------------
// Y[row, c] = outdeg^-1/2 * (A[row,:] @ Wt[c,:]);  BM=128 x BN=384, BK=32.
// 8 waves (2m x 4n), wave tile 64x96. A staged once per tile for ALL 3 relations.
// 3 LDS buffers, 2-deep prefetch, counted vmcnt, ONE s_barrier per K-step. No setprio.
// AFFINE (layer 1): A is f32 Z; BN affine v*ab[ch]+ab[128+ch] applied during cvt,
// ab table staged to LDS in prologue so affine reads never touch vmcnt.
template<int K, bool AF32, bool AFFINE>
__global__ __launch_bounds__(512)
void k_gemm_pipe(const void* __restrict__ Av,
                 const u16* __restrict__ Wt,     // [384][K] bf16
                 const float* __restrict__ soutRaw, // [3][NN] raw out-degrees
                 const float* __restrict__ abg,  // [256] affine (AFFINE only)
                 u16* __restrict__ Y,            // [M][384] bf16
                 int M)
{
  constexpr int A_BYTES = AF32 ? (128 * 32 * 4) : (128 * 32 * 2);  // 16 KB / 8 KB
  constexpr int B_BYTES = 384 * 32 * 2;                            // 24 KB
  constexpr int BUF_U16 = (A_BYTES + B_BYTES) / 2;
  __shared__ u16 lds[3][BUF_U16];   // 120 KB (AF32) / 96 KB
  __shared__ float abl[256];        // affine table (AFFINE only)

  const int row0 = blockIdx.x * 128;
  const int t    = threadIdx.x;
  const int lane = t & 63;
  const int w    = t >> 6;          // 0..7
  const int wm   = w >> 2;          // 0..1
  const int wn   = w & 3;           // 0..3
  const int l15  = lane & 15, l4 = lane >> 4;
  const int kl   = l4 * 8;
  const int nk   = K / 32;

  int ar = row0 + w * 16 + l15;  if (ar >= M) ar = M - 1;   // clamped dup read

  const float* Af = (const float*)Av;
  const u16*   Ab = (const u16*)Av;

  const u16* gb0 = Wt + (size_t)(w * 48 +      l15) * K + kl;
  const u16* gb1 = Wt + (size_t)(w * 48 + 16 + l15) * K + kl;
  const u16* gb2 = Wt + (size_t)(w * 48 + 32 + l15) * K + kl;

  auto STAGE = [&](int buf, int k0) {
    u16* L = &lds[buf][0];
    if constexpr (AF32) {
      const float* sa = Af + (size_t)ar * K + k0 + kl;
      __builtin_amdgcn_global_load_lds(AS1(sa),     AS3(L + (w * 2048) / 2),          16, 0, 0);
      __builtin_amdgcn_global_load_lds(AS1(sa + 4), AS3(L + (w * 2048 + 1024) / 2),   16, 0, 0);
    } else {
      const u16* sa = Ab + (size_t)ar * K + k0 + kl;
      __builtin_amdgcn_global_load_lds(AS1(sa),     AS3(L + (w * 1024) / 2),          16, 0, 0);
    }
    u16* Bd = L + A_BYTES / 2;
    __builtin_amdgcn_global_load_lds(AS1(gb0 + k0), AS3(Bd + (w * 3 + 0) * 512), 16, 0, 0);
    __builtin_amdgcn_global_load_lds(AS1(gb1 + k0), AS3(Bd + (w * 3 + 1) * 512), 16, 0, 0);
    __builtin_amdgcn_global_load_lds(AS1(gb2 + k0), AS3(Bd + (w * 3 + 2) * 512), 16, 0, 0);
  };

  // affine table to LDS BEFORE staging (its vmcnt retires before the pipeline starts)
  if constexpr (AFFINE) {
    if (t < 256) abl[t] = abg[t];
  }

  f32x4 acc[4][6];
#pragma unroll
  for (int m = 0; m < 4; ++m)
#pragma unroll
    for (int n = 0; n < 6; ++n) acc[m][n] = (f32x4){0.f, 0.f, 0.f, 0.f};

  STAGE(0, 0);
  if (nk > 1) STAGE(1, 32);

  for (int k = 0; k < nk; ++k) {
    if (k + 1 < nk) {
      if constexpr (AF32) asm volatile("s_waitcnt vmcnt(5)" ::: "memory");
      else                asm volatile("s_waitcnt vmcnt(4)" ::: "memory");
    } else {
      asm volatile("s_waitcnt vmcnt(0)" ::: "memory");
    }
    __builtin_amdgcn_sched_barrier(0);
    __builtin_amdgcn_s_barrier();
    __builtin_amdgcn_sched_barrier(0);

    if (k + 2 < nk) STAGE((k + 2) % 3, (k + 2) * 32);

    const int cur = k % 3;
    const int k0 = k * 32;
    bf16x8 a[4], b[6];
    if constexpr (AF32) {
      f32x4 s1, s2, s3, s4;
      if constexpr (AFFINE) {
        s1 = *(const f32x4*)&abl[k0 + kl];            // ab  for ch j=0..3
        s2 = *(const f32x4*)&abl[k0 + kl + 4];        // ab  for ch j=4..7
        s3 = *(const f32x4*)&abl[128 + k0 + kl];      // ab2 lo
        s4 = *(const f32x4*)&abl[128 + k0 + kl + 4];  // ab2 hi
      }
      const float* Al = (const float*)&lds[cur][0];
#pragma unroll
      for (int m = 0; m < 4; ++m) {
        f32x4 lo = *(const f32x4*)&Al[(wm * 4 + m) * 512 + lane * 4];
        f32x4 hi = *(const f32x4*)&Al[(wm * 4 + m) * 512 + 256 + lane * 4];
        union { bf16x8 v; u16 u[8]; } q;
#pragma unroll
        for (int j = 0; j < 4; ++j) {
          float vlo = lo[j], vhi = hi[j];
          if constexpr (AFFINE) {
            vlo = fmaf(vlo, s1[j], s3[j]);
            vhi = fmaf(vhi, s2[j], s4[j]);
          }
          q.u[j]     = __builtin_bit_cast(u16, __float2bfloat16(vlo));
          q.u[4 + j] = __builtin_bit_cast(u16, __float2bfloat16(vhi));
        }
        a[m] = q.v;
      }
    } else {
      const u16* Al = &lds[cur][0];
#pragma unroll
      for (int m = 0; m < 4; ++m) a[m] = *(const bf16x8*)&Al[(wm * 4 + m) * 512 + lane * 8];
    }
    {
      const u16* Bl = &lds[cur][A_BYTES / 2];
#pragma unroll
      for (int n = 0; n < 6; ++n) b[n] = *(const bf16x8*)&Bl[(wn * 6 + n) * 512 + lane * 8];
    }

#pragma unroll
    for (int m = 0; m < 4; ++m)
#pragma unroll
      for (int n = 0; n < 6; ++n)
        acc[m][n] = __builtin_amdgcn_mfma_f32_16x16x32_bf16(a[m], b[n], acc[m][n], 0, 0, 0);
  }

  // epilogue: C layout col=lane&15, row=(lane>>4)*4+reg; out-degree scale inlined rsqrt
#pragma unroll
  for (int m = 0; m < 4; ++m) {
    const int rb = row0 + wm * 64 + m * 16 + l4 * 4;
#pragma unroll
    for (int j = 0; j < 4; ++j) {
      const int row = rb + j;
      if (row < M) {
        u16* yrow = Y + (size_t)row * 384;
#pragma unroll
        for (int n = 0; n < 6; ++n) {
          const int c = wn * 96 + n * 16;
          const float sc = rsqrtf(fmaxf(soutRaw[(size_t)(c >> 7) * NN + row], 1.f));
          yrow[c + l15] = f2b(acc[m][n][j] * sc);
        }
      }
    }
  }
}

// ---------------- unified CSR gather (rel packed in tag, unroll 8, inline rsqrt) ----------------
static __global__ __launch_bounds__(256)
void k_gather(const int* __restrict__ off, const int* __restrict__ srt,
              const float* __restrict__ sinRaw, const u16* __restrict__ Y,
              const float* __restrict__ b, u16* __restrict__ acc16)
{
  int d = blockIdx.x * 4 + (threadIdx.x >> 6);
  if (d >= NN) return;
  int c = (threadIdx.x & 63) * 2;
  float v0 = b[c]     + b[128 + c]     + b[256 + c];
  float v1 = b[c + 1] + b[128 + c + 1] + b[256 + c + 1];
  const float sc0 = rsqrtf(fmaxf(sinRaw[d], 1.f));
  const float sc1 = rsqrtf(fmaxf(sinRaw[NN + d], 1.f));
  const float sc2 = rsqrtf(fmaxf(sinRaw[2 * NN + d], 1.f));
  int j0 = off[d], j1 = off[d + 1];
  int j = j0;
  for (; j + 8 <= j1; j += 8) {
    unsigned uu[8];
    int rr[8];
#pragma unroll
    for (int q = 0; q < 8; ++q) {
      int tg = srt[j + q];
      rr[q] = tg & 3;
      uu[q] = *(const unsigned*)&Y[(size_t)(tg >> 2) * 384 + (size_t)rr[q] * 128 + c];
    }
#pragma unroll
    for (int q = 0; q < 8; ++q) {
      float s = (rr[q] == 0) ? sc0 : ((rr[q] == 1) ? sc1 : sc2);
      v0 = fmaf(b2f((u16)(uu[q] & 0xFFFFu)), s, v0);
      v1 = fmaf(b2f((u16)(uu[q] >> 16)), s, v1);
    }
  }
  for (; j < j1; ++j) {
    int tg = srt[j];
    int r = tg & 3;
    unsigned u = *(const unsigned*)&Y[(size_t)(tg >> 2) * 384 + (size_t)r * 128 + c];
    float s = (r == 0) ? sc0 : ((r == 1) ? sc1 : sc2);
    v0 = fmaf(b2f((u16)(u & 0xFFFFu)), s, v0);
    v1 = fmaf(b2f((u16)(u >> 16)), s, v1);
  }
  unsigned o = (unsigned)f2b(v0) | ((unsigned)f2b(v1) << 16);
  *(unsigned*)&acc16[(size_t)d * 128 + c] = o;
}

// ---------------- FC (128x128) via MFMA + fused BN-stats ----------------
static __global__ __launch_bounds__(512)
void k_fc_mfma(const u16* __restrict__ A,      // [M][128] bf16
               const u16* __restrict__ Bt,     // [128][128] bf16 (row=outcol)
               const float* __restrict__ bias,
               float* __restrict__ Z, float* __restrict__ stats, int M)
{
  __shared__ u16 Ab[4][4096];   // 32 KB
  __shared__ float sst[256];

  const int row0 = blockIdx.x * 128;
  const int t    = threadIdx.x;
  const int lane = t & 63;
  const int w    = t >> 6;
  const int wm   = w >> 2;          // 0..1
  const int wn   = w & 3;           // 0..3
  const int l15  = lane & 15, l4 = lane >> 4;
  const int kl   = l4 * 8;

  if (t < 256) sst[t] = 0.f;

  int ar = row0 + w * 16 + l15;  if (ar >= M) ar = M - 1;

  bf16x8 br[2][4];
#pragma unroll
  for (int n = 0; n < 2; ++n)
#pragma unroll
    for (int ks = 0; ks < 4; ++ks)
      br[n][ks] = *(const bf16x8*)&Bt[(size_t)(wn * 32 + n * 16 + l15) * 128 + ks * 32 + kl];

#pragma unroll
  for (int ks = 0; ks < 4; ++ks)
    __builtin_amdgcn_global_load_lds(AS1(A + (size_t)ar * 128 + ks * 32 + kl),
                                     AS3(&Ab[ks][w * 512]), 16, 0, 0);

  asm volatile("s_waitcnt vmcnt(0)" ::: "memory");
  __syncthreads();

  f32x4 acc[4][2];
#pragma unroll
  for (int m = 0; m < 4; ++m) { acc[m][0] = (f32x4){0,0,0,0}; acc[m][1] = (f32x4){0,0,0,0}; }

#pragma unroll
  for (int ks = 0; ks < 4; ++ks) {
#pragma unroll
    for (int m = 0; m < 4; ++m) {
      bf16x8 a = *(const bf16x8*)&Ab[ks][(wm * 4 + m) * 512 + lane * 8];
      acc[m][0] = __builtin_amdgcn_mfma_f32_16x16x32_bf16(a, br[0][ks], acc[m][0], 0, 0, 0);
      acc[m][1] = __builtin_amdgcn_mfma_f32_16x16x32_bf16(a, br[1][ks], acc[m][1], 0, 0, 0);
    }
  }

  float ps[2] = {0.f, 0.f}, ps2[2] = {0.f, 0.f};
#pragma unroll
  for (int m = 0; m < 4; ++m) {
    const int rb = row0 + wm * 64 + m * 16 + l4 * 4;
#pragma unroll
    for (int j = 0; j < 4; ++j) {
      const int row = rb + j;
      const bool ok = row < M;
#pragma unroll
      for (int n = 0; n < 2; ++n) {
        const int cc = wn * 32 + n * 16 + l15;
        float v = ok ? fmaxf(acc[m][n][j] + bias[cc], 0.f) : 0.f;
        if (ok) Z[(size_t)row * 128 + cc] = v;
        ps[n]  += v;
        ps2[n] += v * v;
      }
    }
  }
#pragma unroll
  for (int n = 0; n < 2; ++n) {
    ps[n]  += __shfl_xor(ps[n], 16);  ps[n]  += __shfl_xor(ps[n], 32);
    ps2[n] += __shfl_xor(ps2[n], 16); ps2[n] += __shfl_xor(ps2[n], 32);
  }
  if (l4 == 0) {
#pragma unroll
    for (int n = 0; n < 2; ++n) {
      const int cc = wn * 32 + n * 16 + l15;
      atomicAdd(&sst[cc], ps[n]);
      atomicAdd(&sst[128 + cc], ps2[n]);
    }
  }
  __syncthreads();
  if (t < 256) atomicAdd(&stats[t], sst[t]);
}

// ---------------- BatchNorm finalize / final apply ----------------
static __global__ void k_bn_finalize(const float* __restrict__ stats, int M,
                                     const float* __restrict__ g, const float* __restrict__ beta,
                                     float* __restrict__ ab) {
  int j = threadIdx.x;  // 128
  float m  = stats[j] / (float)M;
  float v  = stats[128 + j] / (float)M - m * m;
  float inv = rsqrtf(v + EPSV) * g[j];
  ab[j]       = inv;
  ab[128 + j] = beta[j] - m * inv;
}

static __global__ void k_bn_apply_f32(const float* __restrict__ Z, const float* __restrict__ ab,
                                      float* __restrict__ out, int n) {
  int i = blockIdx.x * blockDim.x + threadIdx.x;
  if (i < n) {
    int j = i & 127;
    out[i] = Z[i] * ab[j] + ab[128 + j];
  }
}

extern "C" void kernel_launch(void* const* d_in, const int* in_sizes, int n_in,
                              void* d_out, int out_size, void* d_ws, size_t ws_size,
                              hipStream_t stream)
{
  const float* x    = (const float*)d_in[0];
  const int*   seq  = (const int*)d_in[1];
  const int*   knn  = (const int*)d_in[2];
  const int*   dis  = (const int*)d_in[3];
  const float* W0   = (const float*)d_in[4];
  const float* b0   = (const float*)d_in[5];
  const float* fcW0 = (const float*)d_in[6];
  const float* fcb0 = (const float*)d_in[7];
  const float* g0   = (const float*)d_in[8];
  const float* be0  = (const float*)d_in[9];
  const float* W1   = (const float*)d_in[10];
  const float* b1   = (const float*)d_in[11];
  const float* fcW1 = (const float*)d_in[12];
  const float* fcb1 = (const float*)d_in[13];
  const float* g1   = (const float*)d_in[14];
  const float* be1  = (const float*)d_in[15];

  const int E0 = in_sizes[1] / 2, E1 = in_sizes[2] / 2, E2 = in_sizes[3] / 2;
  const int ETOT = E0 + E1 + E2;

  const size_t N = NN;

  float* ws    = (float*)d_ws;
  float* sOut  = ws;                        // 3N raw out-degrees
  float* sIn   = sOut + 3 * N;              // 3N raw in-degrees
  u16*   acc16 = (u16*)(sIn + 3 * N);       // N*128 bf16
  float* stats = (float*)(acc16 + N * 128); // 512 (L0: [0..256), L1: [256..512))
  float* ab0   = stats + 512;               // 256
  float* ab1   = ab0 + 256;                 // 256
  u16*   Y     = (u16*)(ab1 + 256);         // N*384 bf16
  float* Z     = (float*)(Y + N * 384);     // N*128 f32 (own region: gemm1 reads it)
  u16*   Wt0   = (u16*)(Z + N * 128);       // 3*128*1280
  u16*   Wt1   = Wt0 + 3 * 128 * 1280;      // 3*128*128
  u16*   fcWt0 = Wt1 + 3 * 128 * 128;       // 128*128
  u16*   fcWt1 = fcWt0 + 128 * 128;         // 128*128
  int*   off   = (int*)(fcWt1 + 128 * 128); // N+1
  int*   aux   = off + (NN + 1);            // scan aux (<=1536)
  int*   cur   = aux + 1536;                // N
  int*   srt   = cur + NN;                  // ETOT
  // total ~183 MB

  const int NT = (NN + 127) / 128;

  // ---- preprocessing (7 dispatches) ----
  k_init<<<(6 * NN + 255) / 256, 256, 0, stream>>>(sOut, 6 * NN, cur, NN, stats, 512);
  k_deg_all<<<(ETOT + 255) / 256, 256, 0, stream>>>(seq, knn, dis, E0, E1, E2, sOut, sIn);

  const int nsc = NN + 1;
  const int nb  = (nsc + 255) / 256;
  k_scan1_c<<<nb, 256, 0, stream>>>(sIn, off, aux, nsc);
  k_scan2<<<1, 256, 0, stream>>>(aux, nb);
  k_scan3<<<nb, 256, 0, stream>>>(off, aux, nsc);

  k_fill_all<<<(ETOT + 255) / 256, 256, 0, stream>>>(seq, knn, dis, E0, E1, E2, off, cur, srt);

  const int CVT_TOT = 3 * 1280 * 128 + 3 * 128 * 128 + 2 * 128 * 128;
  k_cvt_all<<<(CVT_TOT + 255) / 256, 256, 0, stream>>>(W0, W1, fcW0, fcW1, Wt0, Wt1, fcWt0, fcWt1);

  // ---- layer 0: x f32 [N,1280] -> Z f32 [N,128] (pre-BN), ab0 ----
  k_gemm_pipe<1280, true, false><<<NT, 512, 0, stream>>>(x, Wt0, sOut, nullptr, Y, NN);
  k_gather<<<(NN + 3) / 4, 256, 0, stream>>>(off, srt, sIn, Y, b0, acc16);
  k_fc_mfma<<<NT, 512, 0, stream>>>(acc16, fcWt0, fcb0, Z, stats, NN);
  k_bn_finalize<<<1, 128, 0, stream>>>(stats, NN, g0, be0, ab0);

  // ---- layer 1: gemm reads Z + applies ab0 in the cvt (BN-apply fused) ----
  k_gemm_pipe<128, true, true><<<NT, 512, 0, stream>>>(Z, Wt1, sOut, ab0, Y, NN);
  k_gather<<<(NN + 3) / 4, 256, 0, stream>>>(off, srt, sIn, Y, b1, acc16);
  k_fc_mfma<<<NT, 512, 0, stream>>>(acc16, fcWt1, fcb1, Z, stats + 256, NN);
  k_bn_finalize<<<1, 128, 0, stream>>>(stats + 256, NN, g1, be1, ab1);
  k_bn_apply_f32<<<(NN * HID + 255) / 256, 256, 0, stream>>>(Z, ab1, (float*)d_out, NN * HID);
}